// Round 2
// baseline (5369.358 us; speedup 1.0000x reference)
//
#include <hip/hip_runtime.h>

#define HH 256   // hidden size
#define KK 8     // max neighbors
#define NB 8     // nodes per block

__device__ __forceinline__ float sigmoidf(float x) {
    return 1.0f / (1.0f + __expf(-x));
}

__global__ __launch_bounds__(256, 2)
void conv_enc_fp32(const float* __restrict__ prev,
                   const float* __restrict__ W_U,
                   const float* __restrict__ W_V,
                   const float* __restrict__ W_A,
                   const float* __restrict__ W_B,
                   const int* __restrict__ parent,
                   const int* __restrict__ child,
                   const int* __restrict__ mask,   // jnp.bool_ materialized as int32
                   float* __restrict__ out,
                   int n_nodes)
{
    __shared__ float ph[NB][HH];   // parent rows
    __shared__ float cs[NB][HH];   // sum of unmasked child rows
    __shared__ float chk[KK][HH];  // one node's child rows (B phase)

    const int tid = threadIdx.x;        // output channel i
    const int e0  = blockIdx.x * NB;
    const int nb  = min(NB, n_nodes - e0);

    // ---- stage parent rows and child-sums (coalesced gathers) ----
    for (int n = 0; n < NB; ++n) {
        const int e = e0 + n;
        if (n < nb) {
            const int p = parent[e];
            ph[n][tid] = prev[(size_t)p * HH + tid];
            float c = 0.f;
            #pragma unroll
            for (int k = 0; k < KK; ++k) {
                if (mask[(size_t)e * KK + k] != 0) {
                    const int ci = child[(size_t)e * KK + k];
                    c += prev[(size_t)ci * HH + tid];
                }
            }
            cs[n][tid] = c;
        } else {
            ph[n][tid] = 0.f;
            cs[n][tid] = 0.f;
        }
    }
    __syncthreads();

    // ---- A/U/V dots, batched over NB nodes per W-row read ----
    float accA[NB], accU[NB], accV[NB];
    #pragma unroll
    for (int n = 0; n < NB; ++n) { accA[n] = 0.f; accU[n] = 0.f; accV[n] = 0.f; }

    const float4* WA4 = reinterpret_cast<const float4*>(W_A) + (size_t)tid * (HH / 4);
    const float4* WU4 = reinterpret_cast<const float4*>(W_U) + (size_t)tid * (HH / 4);
    const float4* WV4 = reinterpret_cast<const float4*>(W_V) + (size_t)tid * (HH / 4);

    for (int h4 = 0; h4 < HH / 4; ++h4) {
        const float4 wa = WA4[h4];
        const float4 wu = WU4[h4];
        const float4 wv = WV4[h4];
        #pragma unroll
        for (int n = 0; n < NB; ++n) {
            const float4 xp = reinterpret_cast<const float4*>(ph[n])[h4];
            const float4 xc = reinterpret_cast<const float4*>(cs[n])[h4];
            accA[n] = fmaf(wa.x, xp.x, fmaf(wa.y, xp.y, fmaf(wa.z, xp.z, fmaf(wa.w, xp.w, accA[n]))));
            accU[n] = fmaf(wu.x, xp.x, fmaf(wu.y, xp.y, fmaf(wu.z, xp.z, fmaf(wu.w, xp.w, accU[n]))));
            accV[n] = fmaf(wv.x, xc.x, fmaf(wv.y, xc.y, fmaf(wv.z, xc.z, fmaf(wv.w, xc.w, accV[n]))));
        }
    }

    // ---- B dots: per node, all K child slots batched per W_B-row read ----
    const float4* WB4 = reinterpret_cast<const float4*>(W_B) + (size_t)tid * (HH / 4);

    for (int n = 0; n < nb; ++n) {
        const int e = e0 + n;

        __syncthreads();   // previous iteration's chk reads complete
        unsigned um = 0;   // bitmask of unmasked slots (uniform across block)
        #pragma unroll
        for (int k = 0; k < KK; ++k) {
            const bool m = mask[(size_t)e * KK + k] != 0;
            um |= (unsigned)m << k;
            chk[k][tid] = m ? prev[(size_t)child[(size_t)e * KK + k] * HH + tid] : 0.f;
        }
        __syncthreads();

        float accB[KK];
        #pragma unroll
        for (int k = 0; k < KK; ++k) accB[k] = 0.f;

        for (int h4 = 0; h4 < HH / 4; ++h4) {
            const float4 wb = WB4[h4];
            #pragma unroll
            for (int k = 0; k < KK; ++k) {
                const float4 xk = reinterpret_cast<const float4*>(chk[k])[h4];
                accB[k] = fmaf(wb.x, xk.x, fmaf(wb.y, xk.y, fmaf(wb.z, xk.z, fmaf(wb.w, xk.w, accB[k]))));
            }
        }

        // epilogue: eta-sum = n_masked*sigmoid(A) + sum_unmasked sigmoid(A+B_k)
        const float A = accA[n];
        float s = (float)(KK - __popc(um)) * sigmoidf(A);
        #pragma unroll
        for (int k = 0; k < KK; ++k) {
            if ((um >> k) & 1u) s += sigmoidf(A + accB[k]);
        }
        const float o = accU[n] + accV[n] + s;
        out[(size_t)parent[e] * HH + tid] = (o > 0.f) ? o : 0.f;
    }
}

extern "C" void kernel_launch(void* const* d_in, const int* in_sizes, int n_in,
                              void* d_out, int out_size, void* d_ws, size_t ws_size,
                              hipStream_t stream)
{
    const float* prev = (const float*)d_in[0];
    const float* W_U  = (const float*)d_in[1];
    const float* W_V  = (const float*)d_in[2];
    const float* W_A  = (const float*)d_in[3];
    const float* W_B  = (const float*)d_in[4];
    const int*   parent = (const int*)d_in[5];
    const int*   child  = (const int*)d_in[6];
    const int*   mask   = (const int*)d_in[7];
    float* out = (float*)d_out;

    const int n_nodes = in_sizes[5];

    // rows not hit by the scatter must be zero (and d_out is poisoned 0xAA)
    hipMemsetAsync(d_out, 0, (size_t)out_size * sizeof(float), stream);

    const int blocks = (n_nodes + NB - 1) / NB;
    conv_enc_fp32<<<blocks, 256, 0, stream>>>(prev, W_U, W_V, W_A, W_B,
                                              parent, child, mask, out, n_nodes);
}

// Round 3
// 748.782 us; speedup vs baseline: 7.1708x; 7.1708x over previous
//
#include <hip/hip_runtime.h>

#define HH 256
#define KK 8
#define BM 32          // nodes per block
#define NTHREADS 512   // 8 waves

typedef __attribute__((ext_vector_type(8))) short s16x8;
typedef __attribute__((ext_vector_type(4))) float f32x4;

__device__ __forceinline__ float bf2f(unsigned short u) {
    unsigned int x = ((unsigned int)u) << 16;
    return __builtin_bit_cast(float, x);
}
__device__ __forceinline__ unsigned short f2bf(float f) {
    unsigned int x = __builtin_bit_cast(unsigned int, f);
    unsigned int r = (x + 0x7fffu + ((x >> 16) & 1u)) >> 16;   // RNE
    return (unsigned short)r;
}
__device__ __forceinline__ float sigmoidf(float x) {
    return 1.0f / (1.0f + __expf(-x));
}

// ---- prep: fp32 -> bf16, 8 elems/thread ----
__global__ void cvt_bf16(const float* __restrict__ src, unsigned short* __restrict__ dst, int n8) {
    int i = blockIdx.x * blockDim.x + threadIdx.x;
    if (i >= n8) return;
    const float4* s = reinterpret_cast<const float4*>(src);
    float4 a = s[i * 2], b = s[i * 2 + 1];
    uint4 o;
    o.x = (unsigned)f2bf(a.x) | ((unsigned)f2bf(a.y) << 16);
    o.y = (unsigned)f2bf(a.z) | ((unsigned)f2bf(a.w) << 16);
    o.z = (unsigned)f2bf(b.x) | ((unsigned)f2bf(b.y) << 16);
    o.w = (unsigned)f2bf(b.z) | ((unsigned)f2bf(b.w) << 16);
    reinterpret_cast<uint4*>(dst)[i] = o;
}

// ---- main fused MFMA kernel ----
__global__ __launch_bounds__(NTHREADS, 2)
void conv_mfma(const unsigned short* __restrict__ pb,   // [N][256] bf16
               const unsigned short* __restrict__ wb,   // [4][256][256] bf16: A,U,V,B
               const int* __restrict__ parent,
               const int* __restrict__ child,
               const int* __restrict__ mask,
               float* __restrict__ out,
               int n_nodes)
{
    __shared__ unsigned short ph[BM * HH];   // parent tile (swizzled)
    __shared__ unsigned short chk[BM * HH];  // current child-slot tile
    __shared__ unsigned short cs[BM * HH];   // child-sum tile (bf16 accum)

    const int tid  = threadIdx.x;
    const int e0   = blockIdx.x * BM;
    const int nb   = min(BM, n_nodes - e0);
    const int lane = tid & 63;
    const int wid  = tid >> 6;
    const int rg   = wid >> 2;      // row group (16 rows each)
    const int q    = wid & 3;       // col quarter (64 cols)
    const int lm   = lane & 15;
    const int kc   = lane >> 4;     // k-chunk 0..3

    const unsigned short* WA = wb;
    const unsigned short* WU = wb + 65536;
    const unsigned short* WV = wb + 2 * 65536;
    const unsigned short* WB_ = wb + 3 * 65536;

    // ---- stage parent tile (swizzled: byte ^= (row&7)<<4) ----
    for (int c = tid; c < BM * 32; c += NTHREADS) {
        const int row = c >> 5, cc = c & 31;
        uint4 v = {0u, 0u, 0u, 0u};
        if (row < nb) {
            const int p = parent[e0 + row];
            v = *reinterpret_cast<const uint4*>(pb + (size_t)p * HH + cc * 8);
        }
        const int byte = row * 512 + ((cc * 16) ^ ((row & 7) << 4));
        *reinterpret_cast<uint4*>(reinterpret_cast<char*>(ph) + byte) = v;
    }
    __syncthreads();

    // a-frag byte offset within a tile, for this lane's (rg,lm,kc)
    const int m_local = rg * 16 + lm;
    // per-k0 addresses: m_local*512 + ((k0*64 + kc*16) ^ ((m_local&7)<<4))

    // ---- GEMM A = ph @ W_A^T ----
    f32x4 accA[4];
    #pragma unroll
    for (int t = 0; t < 4; ++t) accA[t] = (f32x4){0.f, 0.f, 0.f, 0.f};
    {
        const char* phc = reinterpret_cast<const char*>(ph);
        const char* wc  = reinterpret_cast<const char*>(WA);
        #pragma unroll
        for (int k0 = 0; k0 < 8; ++k0) {
            const int ab = m_local * 512 + (((k0 * 64) + kc * 16) ^ ((m_local & 7) << 4));
            s16x8 a = *reinterpret_cast<const s16x8*>(phc + ab);
            #pragma unroll
            for (int t = 0; t < 4; ++t) {
                const int n = q * 64 + t * 16 + lm;
                s16x8 b = *reinterpret_cast<const s16x8*>(wc + n * 512 + k0 * 64 + kc * 16);
                accA[t] = __builtin_amdgcn_mfma_f32_16x16x32_bf16(a, b, accA[t], 0, 0, 0);
            }
        }
    }

    // ---- slot loop: stage ch_k, accumulate cs, GEMM B_k, eta sum ----
    f32x4 etas[4];
    #pragma unroll
    for (int t = 0; t < 4; ++t) etas[t] = (f32x4){0.f, 0.f, 0.f, 0.f};

    for (int s = 0; s < KK; ++s) {
        __syncthreads();   // previous chk consumers done
        for (int c = tid; c < BM * 32; c += NTHREADS) {
            const int row = c >> 5, cc = c & 31;
            uint4 v = {0u, 0u, 0u, 0u};
            if (row < nb) {
                const int m = mask[(size_t)(e0 + row) * KK + s];
                if (m) {
                    const int ci = child[(size_t)(e0 + row) * KK + s];
                    v = *reinterpret_cast<const uint4*>(pb + (size_t)ci * HH + cc * 8);
                }
            }
            const int byte = row * 512 + ((cc * 16) ^ ((row & 7) << 4));
            *reinterpret_cast<uint4*>(reinterpret_cast<char*>(chk) + byte) = v;
        }
        __syncthreads();

        // cs += chk (bf16), same swizzled addressing; no one reads cs until after loop
        for (int c = tid; c < BM * 32; c += NTHREADS) {
            const int byte = (c >> 5) * 512 + (((c & 31) * 16) ^ (((c >> 5) & 7) << 4));
            uint4 cv = *reinterpret_cast<const uint4*>(reinterpret_cast<const char*>(chk) + byte);
            if (s == 0) {
                *reinterpret_cast<uint4*>(reinterpret_cast<char*>(cs) + byte) = cv;
            } else {
                uint4 ov = *reinterpret_cast<const uint4*>(reinterpret_cast<const char*>(cs) + byte);
                unsigned short* cp = reinterpret_cast<unsigned short*>(&cv);
                unsigned short* op = reinterpret_cast<unsigned short*>(&ov);
                #pragma unroll
                for (int j = 0; j < 8; ++j) op[j] = f2bf(bf2f(op[j]) + bf2f(cp[j]));
                *reinterpret_cast<uint4*>(reinterpret_cast<char*>(cs) + byte) = ov;
            }
        }

        // GEMM B_s = chk @ W_B^T (transient accumulator)
        f32x4 accB[4];
        #pragma unroll
        for (int t = 0; t < 4; ++t) accB[t] = (f32x4){0.f, 0.f, 0.f, 0.f};
        {
            const char* xc = reinterpret_cast<const char*>(chk);
            const char* wc = reinterpret_cast<const char*>(WB_);
            #pragma unroll
            for (int k0 = 0; k0 < 8; ++k0) {
                const int ab = m_local * 512 + (((k0 * 64) + kc * 16) ^ ((m_local & 7) << 4));
                s16x8 a = *reinterpret_cast<const s16x8*>(xc + ab);
                #pragma unroll
                for (int t = 0; t < 4; ++t) {
                    const int n = q * 64 + t * 16 + lm;
                    s16x8 b = *reinterpret_cast<const s16x8*>(wc + n * 512 + k0 * 64 + kc * 16);
                    accB[t] = __builtin_amdgcn_mfma_f32_16x16x32_bf16(a, b, accB[t], 0, 0, 0);
                }
            }
        }
        #pragma unroll
        for (int t = 0; t < 4; ++t) {
            #pragma unroll
            for (int r = 0; r < 4; ++r)
                etas[t][r] += sigmoidf(accA[t][r] + accB[t][r]);
        }
    }
    __syncthreads();   // cs complete before V GEMM

    // ---- GEMM UV = ph @ W_U^T + cs @ W_V^T ----
    f32x4 accUV[4];
    #pragma unroll
    for (int t = 0; t < 4; ++t) accUV[t] = (f32x4){0.f, 0.f, 0.f, 0.f};
    {
        const char* phc = reinterpret_cast<const char*>(ph);
        const char* csc = reinterpret_cast<const char*>(cs);
        const char* wu  = reinterpret_cast<const char*>(WU);
        const char* wv  = reinterpret_cast<const char*>(WV);
        #pragma unroll
        for (int k0 = 0; k0 < 8; ++k0) {
            const int ab = m_local * 512 + (((k0 * 64) + kc * 16) ^ ((m_local & 7) << 4));
            s16x8 au = *reinterpret_cast<const s16x8*>(phc + ab);
            s16x8 av = *reinterpret_cast<const s16x8*>(csc + ab);
            #pragma unroll
            for (int t = 0; t < 4; ++t) {
                const int n = q * 64 + t * 16 + lm;
                s16x8 bu = *reinterpret_cast<const s16x8*>(wu + n * 512 + k0 * 64 + kc * 16);
                s16x8 bv = *reinterpret_cast<const s16x8*>(wv + n * 512 + k0 * 64 + kc * 16);
                accUV[t] = __builtin_amdgcn_mfma_f32_16x16x32_bf16(au, bu, accUV[t], 0, 0, 0);
                accUV[t] = __builtin_amdgcn_mfma_f32_16x16x32_bf16(av, bv, accUV[t], 0, 0, 0);
            }
        }
    }

    // ---- epilogue: relu(UV + etas), scatter ----
    #pragma unroll
    for (int r = 0; r < 4; ++r) {
        const int row = rg * 16 + kc * 4 + r;      // D: row=(lane>>4)*4+reg
        if (row < nb) {
            const size_t orow = (size_t)parent[e0 + row] * HH;
            #pragma unroll
            for (int t = 0; t < 4; ++t) {
                float v = accUV[t][r] + etas[t][r];
                v = v > 0.f ? v : 0.f;
                out[orow + q * 64 + t * 16 + lm] = v;
            }
        }
    }
}

extern "C" void kernel_launch(void* const* d_in, const int* in_sizes, int n_in,
                              void* d_out, int out_size, void* d_ws, size_t ws_size,
                              hipStream_t stream)
{
    const float* prev = (const float*)d_in[0];
    const float* W_U  = (const float*)d_in[1];
    const float* W_V  = (const float*)d_in[2];
    const float* W_A  = (const float*)d_in[3];
    const float* W_B  = (const float*)d_in[4];
    const int* parent = (const int*)d_in[5];
    const int* child  = (const int*)d_in[6];
    const int* mask   = (const int*)d_in[7];
    float* out = (float*)d_out;

    const int n_nodes = in_sizes[5];
    const int prev_elems = in_sizes[0];          // N*256

    unsigned short* pb = (unsigned short*)d_ws;                    // [N][256] bf16
    unsigned short* wb = pb + (size_t)prev_elems;                  // [4][256][256] bf16

    // prep: bf16 conversions
    {
        int n8 = prev_elems / 8;
        cvt_bf16<<<(n8 + 255) / 256, 256, 0, stream>>>(prev, pb, n8);
        int w8 = 65536 / 8;
        cvt_bf16<<<(w8 + 255) / 256, 256, 0, stream>>>(W_A, wb,             w8);
        cvt_bf16<<<(w8 + 255) / 256, 256, 0, stream>>>(W_U, wb + 65536,     w8);
        cvt_bf16<<<(w8 + 255) / 256, 256, 0, stream>>>(W_V, wb + 2 * 65536, w8);
        cvt_bf16<<<(w8 + 255) / 256, 256, 0, stream>>>(W_B, wb + 3 * 65536, w8);
    }

    hipMemsetAsync(d_out, 0, (size_t)out_size * sizeof(float), stream);

    const int blocks = (n_nodes + BM - 1) / BM;
    conv_mfma<<<blocks, NTHREADS, 0, stream>>>(pb, wb, parent, child, mask, out, n_nodes);
}

// Round 4
// 673.140 us; speedup vs baseline: 7.9766x; 1.1124x over previous
//
#include <hip/hip_runtime.h>

#define HH 256
#define KK 8

typedef __attribute__((ext_vector_type(8))) short s16x8;
typedef __attribute__((ext_vector_type(4))) float f32x4;

__device__ __forceinline__ float bf2f(unsigned short u){ unsigned x=((unsigned)u)<<16; return __builtin_bit_cast(float,x); }
__device__ __forceinline__ unsigned short f2bf(float f){ unsigned x=__builtin_bit_cast(unsigned,f); return (unsigned short)((x+0x7fffu+((x>>16)&1u))>>16); }
__device__ __forceinline__ float sigmoidf(float x){ return 1.0f/(1.0f+__expf(-x)); }

// ---- K1: fp32 -> bf16, 8 elems/thread ----
__global__ void cvt_bf16(const float* __restrict__ src, unsigned short* __restrict__ dst, int n8){
  int i = blockIdx.x*blockDim.x + threadIdx.x;
  if (i>=n8) return;
  const float4* s = reinterpret_cast<const float4*>(src);
  float4 a = s[i*2], b = s[i*2+1];
  uint4 o;
  o.x = (unsigned)f2bf(a.x) | ((unsigned)f2bf(a.y)<<16);
  o.y = (unsigned)f2bf(a.z) | ((unsigned)f2bf(a.w)<<16);
  o.z = (unsigned)f2bf(b.x) | ((unsigned)f2bf(b.y)<<16);
  o.w = (unsigned)f2bf(b.z) | ((unsigned)f2bf(b.w)<<16);
  reinterpret_cast<uint4*>(dst)[i] = o;
}

// ---- K2: dst[e] (+)= rowsrc(e) @ W^T,  bf16 out.
// MODE 0: rowsrc = pb[parent[e]]; MODE 1: rowsrc = sum_k (mask ? pb[child[e,k]] : 0)
template<int MODE, int ACCUM>
__global__ __launch_bounds__(512, 2)
void gemm_gather(const unsigned short* __restrict__ pb,
                 const unsigned short* __restrict__ W,      // [256][256] bf16 [out][in]
                 unsigned short* __restrict__ dst,          // [N][256] bf16
                 const int* __restrict__ parent,
                 const int* __restrict__ child,
                 const int* __restrict__ mask,
                 int n)
{
  __shared__ unsigned short inT[64*HH];     // 32KB, swizzled rows
  __shared__ unsigned short wpan[HH*32];    // 16KB, k-panel [n][32k], linear
  const int tid = threadIdx.x;
  const int e0 = blockIdx.x*64;
  const int nb = min(64, n - e0);

  // stage input tile (swizzled: byte ^= (row&7)<<4)
  for (int it=0; it<4; ++it){
    const int c = it*512 + tid;
    const int row = c>>5, ch = c&31;
    uint4 v = {0u,0u,0u,0u};
    if (row < nb){
      if (MODE==0){
        const int p = parent[e0+row];
        v = *reinterpret_cast<const uint4*>(pb + (size_t)p*HH + ch*8);
      } else {
        float acc[8];
        #pragma unroll
        for (int j=0;j<8;++j) acc[j]=0.f;
        const int* mrow = mask  + (size_t)(e0+row)*KK;
        const int* crow = child + (size_t)(e0+row)*KK;
        #pragma unroll
        for (int k=0;k<KK;++k){
          if (mrow[k]){
            uint4 cv = *reinterpret_cast<const uint4*>(pb + (size_t)crow[k]*HH + ch*8);
            const unsigned short* cp = reinterpret_cast<const unsigned short*>(&cv);
            #pragma unroll
            for (int j=0;j<8;++j) acc[j] += bf2f(cp[j]);
          }
        }
        unsigned short r[8];
        #pragma unroll
        for (int j=0;j<8;++j) r[j]=f2bf(acc[j]);
        v.x = (unsigned)r[0] | ((unsigned)r[1]<<16);
        v.y = (unsigned)r[2] | ((unsigned)r[3]<<16);
        v.z = (unsigned)r[4] | ((unsigned)r[5]<<16);
        v.w = (unsigned)r[6] | ((unsigned)r[7]<<16);
      }
    }
    const int byte = row*512 + ((ch*16) ^ ((row&7)<<4));
    *reinterpret_cast<uint4*>(reinterpret_cast<char*>(inT)+byte) = v;
  }

  const int lane = tid&63, wid = tid>>6;
  const int rg = wid>>1, q2 = wid&1;        // 4 row-groups x 2 col-halves
  const int lm = lane&15, kc = lane>>4;
  const int arow = rg*16 + lm;

  f32x4 acc[8];
  #pragma unroll
  for (int t=0;t<8;++t) acc[t]=(f32x4){0.f,0.f,0.f,0.f};

  for (int kp=0; kp<8; ++kp){
    __syncthreads();                         // protects wpan (prev reads / new writes)
    #pragma unroll
    for (int it=0; it<2; ++it){
      const int c = it*512+tid;
      const int nn = c>>2, ch = c&3;
      uint4 v = *reinterpret_cast<const uint4*>(W + (size_t)nn*HH + kp*32 + ch*8);
      *reinterpret_cast<uint4*>(reinterpret_cast<char*>(wpan)+ nn*64 + ch*16) = v;
    }
    __syncthreads();
    const int ab = arow*512 + (((kp*64)+kc*16) ^ ((arow&7)<<4));
    s16x8 a = *reinterpret_cast<const s16x8*>(reinterpret_cast<const char*>(inT)+ab);
    #pragma unroll
    for (int t=0;t<8;++t){
      const int nn = q2*128 + t*16 + lm;
      s16x8 b = *reinterpret_cast<const s16x8*>(reinterpret_cast<const char*>(wpan)+ nn*64 + kc*16);
      acc[t] = __builtin_amdgcn_mfma_f32_16x16x32_bf16(a,b,acc[t],0,0,0);
    }
  }

  // bounce D (bf16) through inT (done with its staged contents), then coalesced flush
  __syncthreads();
  #pragma unroll
  for (int t=0;t<8;++t){
    #pragma unroll
    for (int r=0;r<4;++r){
      const int row = rg*16 + kc*4 + r;      // D: col=lane&15, row=(lane>>4)*4+reg
      const int col = q2*128 + t*16 + lm;
      inT[row*HH + col] = f2bf(acc[t][r]);
    }
  }
  __syncthreads();
  for (int it=0; it<4; ++it){
    const int c = it*512+tid;
    const int row=c>>5, ch=c&31;
    if (row < nb){
      unsigned short* dp = dst + (size_t)(e0+row)*HH + ch*8;
      uint4 v = *reinterpret_cast<const uint4*>(inT + row*HH + ch*8);
      if (ACCUM){
        uint4 o = *reinterpret_cast<const uint4*>(dp);
        const unsigned short* vp=(const unsigned short*)&v;
        const unsigned short* op=(const unsigned short*)&o;
        unsigned short rr[8];
        #pragma unroll
        for(int j=0;j<8;++j) rr[j]=f2bf(bf2f(vp[j])+bf2f(op[j]));
        uint4 w2;
        w2.x=(unsigned)rr[0]|((unsigned)rr[1]<<16);
        w2.y=(unsigned)rr[2]|((unsigned)rr[3]<<16);
        w2.z=(unsigned)rr[4]|((unsigned)rr[5]<<16);
        w2.w=(unsigned)rr[6]|((unsigned)rr[7]<<16);
        *reinterpret_cast<uint4*>(dp)=w2;
      } else {
        *reinterpret_cast<uint4*>(dp)=v;
      }
    }
  }
}

// ---- K3: per (32-e tile) x (128-col half): B-GEMM over 8 slots + eta + epilogue ----
__global__ __launch_bounds__(512, 2)
void eta_epilogue(const unsigned short* __restrict__ pb,
                  const unsigned short* __restrict__ WB,   // [256][256] bf16
                  const unsigned short* __restrict__ Ah,   // [N][256] bf16
                  const unsigned short* __restrict__ UVh,  // [N][256] bf16
                  const int* __restrict__ parent,
                  const int* __restrict__ child,
                  const int* __restrict__ mask,
                  float* __restrict__ out,
                  int n)
{
  __shared__ unsigned short wB[128*HH];   // 64KB: this col-half's W_B rows, swizzled
  __shared__ unsigned short chT[32*HH];   // 16KB: child tile (later reused as f32 bounce)
  const int tid=threadIdx.x;
  const int e0=blockIdx.x*32;
  const int qh=blockIdx.y;                 // column half
  const int lane=tid&63, wid=tid>>6;
  const int rg=wid>>2, qq=wid&3;           // 2 row-groups x 4 col-strips(32)
  const int lm=lane&15, kc=lane>>4;

  // stage W_B half (swizzled rows)
  for (int it=0; it<8; ++it){
    const int c=it*512+tid;
    const int nn=c>>5, ch=c&31;
    uint4 v = *reinterpret_cast<const uint4*>(WB + (size_t)(qh*128+nn)*HH + ch*8);
    const int byte = nn*512 + ((ch*16) ^ ((nn&7)<<4));
    *reinterpret_cast<uint4*>(reinterpret_cast<char*>(wB)+byte)=v;
  }

  // A values for this lane's 2x4 D positions
  float Ar[2][4];
  #pragma unroll
  for (int t=0;t<2;++t){
    #pragma unroll
    for (int r=0;r<4;++r){
      const int row=rg*16+kc*4+r;
      const int col=qh*128+qq*32+t*16+lm;
      Ar[t][r]=bf2f(Ah[(size_t)(e0+row)*HH+col]);
    }
  }

  // per-thread gather coords (2 chunks: rows tid>>5 and +16)
  const int grow0 = tid>>5, gch = tid&31;
  const int grow1 = grow0+16;
  const int* m0 = mask + (size_t)(e0+grow0)*KK;
  const int* c0 = child+ (size_t)(e0+grow0)*KK;
  const int* m1 = mask + (size_t)(e0+grow1)*KK;
  const int* c1 = child+ (size_t)(e0+grow1)*KK;
  const int b0 = grow0*512 + ((gch*16) ^ ((grow0&7)<<4));
  const int b1 = grow1*512 + ((gch*16) ^ ((grow1&7)<<4));

  uint4 p0={0,0,0,0}, p1={0,0,0,0};
  if (m0[0]) p0 = *reinterpret_cast<const uint4*>(pb + (size_t)c0[0]*HH + gch*8);
  if (m1[0]) p1 = *reinterpret_cast<const uint4*>(pb + (size_t)c1[0]*HH + gch*8);
  __syncthreads();          // wB staged; chT not yet read by anyone
  *reinterpret_cast<uint4*>(reinterpret_cast<char*>(chT)+b0)=p0;
  *reinterpret_cast<uint4*>(reinterpret_cast<char*>(chT)+b1)=p1;

  f32x4 etas[2];
  etas[0]=(f32x4){0.f,0.f,0.f,0.f}; etas[1]=(f32x4){0.f,0.f,0.f,0.f};
  const int aoff = (rg*16+lm)*512;
  const int as = (lm&7)<<4;

  for (int s=0;s<8;++s){
    __syncthreads();        // chT slot s visible
    if (s<7){               // prefetch slot s+1 into regs, overlaps GEMM below
      p0=(uint4){0,0,0,0}; p1=(uint4){0,0,0,0};
      if (m0[s+1]) p0=*reinterpret_cast<const uint4*>(pb + (size_t)c0[s+1]*HH + gch*8);
      if (m1[s+1]) p1=*reinterpret_cast<const uint4*>(pb + (size_t)c1[s+1]*HH + gch*8);
    }
    f32x4 accB[2];
    accB[0]=(f32x4){0.f,0.f,0.f,0.f}; accB[1]=(f32x4){0.f,0.f,0.f,0.f};
    #pragma unroll
    for (int k0=0;k0<8;++k0){
      const int kb=k0*64+kc*16;
      s16x8 a = *reinterpret_cast<const s16x8*>(reinterpret_cast<const char*>(chT)+ aoff + (kb^as));
      #pragma unroll
      for (int t=0;t<2;++t){
        const int nl=qq*32+t*16+lm;
        s16x8 b = *reinterpret_cast<const s16x8*>(reinterpret_cast<const char*>(wB)+ nl*512 + (kb^((nl&7)<<4)));
        accB[t]=__builtin_amdgcn_mfma_f32_16x16x32_bf16(a,b,accB[t],0,0,0);
      }
    }
    #pragma unroll
    for (int t=0;t<2;++t){
      #pragma unroll
      for (int r=0;r<4;++r)
        etas[t][r] += sigmoidf(Ar[t][r]+accB[t][r]);
    }
    __syncthreads();        // all chT reads done
    if (s<7){
      *reinterpret_cast<uint4*>(reinterpret_cast<char*>(chT)+b0)=p0;
      *reinterpret_cast<uint4*>(reinterpret_cast<char*>(chT)+b1)=p1;
    }
  }

  // epilogue: relu(UV + etas) -> f32 bounce in chT -> coalesced scatter
  float* ob = reinterpret_cast<float*>(chT);   // 32 x 128 f32 = 16KB
  #pragma unroll
  for (int t=0;t<2;++t){
    #pragma unroll
    for (int r=0;r<4;++r){
      const int row=rg*16+kc*4+r;
      const int col=qq*32+t*16+lm;
      const float uv=bf2f(UVh[(size_t)(e0+row)*HH + qh*128+col]);
      float v=uv+etas[t][r];
      ob[row*128+col]= v>0.f? v:0.f;
    }
  }
  __syncthreads();
  #pragma unroll
  for (int it=0; it<2; ++it){
    const int c=it*512+tid;
    const int row=c>>5, ch=c&31;
    float* op = out + (size_t)parent[e0+row]*HH + qh*128 + ch*4;
    *reinterpret_cast<uint4*>(op) = *reinterpret_cast<const uint4*>(ob + row*128 + ch*4);
  }
}

extern "C" void kernel_launch(void* const* d_in, const int* in_sizes, int n_in,
                              void* d_out, int out_size, void* d_ws, size_t ws_size,
                              hipStream_t stream)
{
  const float* prev = (const float*)d_in[0];
  const float* W_U  = (const float*)d_in[1];
  const float* W_V  = (const float*)d_in[2];
  const float* W_A  = (const float*)d_in[3];
  const float* W_B  = (const float*)d_in[4];
  const int* parent = (const int*)d_in[5];
  const int* child  = (const int*)d_in[6];
  const int* mask   = (const int*)d_in[7];
  float* out = (float*)d_out;

  const int n_nodes = in_sizes[5];
  const size_t prev_elems = (size_t)in_sizes[0];   // N*256

  unsigned short* pb  = (unsigned short*)d_ws;                 // [N][256] bf16
  unsigned short* wb  = pb + prev_elems;                       // [4][256][256] bf16: A,U,V,B
  unsigned short* Ah  = wb + 4*65536;                          // [N][256] bf16
  unsigned short* UVh = Ah + prev_elems;                       // [N][256] bf16

  // K1: conversions
  {
    int n8 = (int)(prev_elems/8);
    cvt_bf16<<<(n8+255)/256, 256, 0, stream>>>(prev, pb, n8);
    int w8 = 65536/8;
    cvt_bf16<<<(w8+255)/256, 256, 0, stream>>>(W_A, wb,           w8);
    cvt_bf16<<<(w8+255)/256, 256, 0, stream>>>(W_U, wb + 65536,   w8);
    cvt_bf16<<<(w8+255)/256, 256, 0, stream>>>(W_V, wb + 2*65536, w8);
    cvt_bf16<<<(w8+255)/256, 256, 0, stream>>>(W_B, wb + 3*65536, w8);
  }

  const int gblocks = (n_nodes + 63)/64;
  // K2: A_h = ph@W_A^T ; UV = ph@W_U^T + cs@W_V^T
  gemm_gather<0,0><<<gblocks, 512, 0, stream>>>(pb, wb,           Ah,  parent, child, mask, n_nodes);
  gemm_gather<0,0><<<gblocks, 512, 0, stream>>>(pb, wb + 65536,   UVh, parent, child, mask, n_nodes);
  gemm_gather<1,1><<<gblocks, 512, 0, stream>>>(pb, wb + 2*65536, UVh, parent, child, mask, n_nodes);

  hipMemsetAsync(d_out, 0, (size_t)out_size * sizeof(float), stream);

  // K3: eta sums + epilogue scatter
  dim3 g3((n_nodes + 31)/32, 2);
  eta_epilogue<<<g3, 512, 0, stream>>>(pb, wb + 3*65536, Ah, UVh,
                                       parent, child, mask, out, n_nodes);
}

// Round 5
// 354.249 us; speedup vs baseline: 15.1570x; 1.9002x over previous
//
#include <hip/hip_runtime.h>

#define HH 256
#define KK 8

typedef __attribute__((ext_vector_type(8))) short s16x8;
typedef __attribute__((ext_vector_type(4))) float f32x4;

__device__ __forceinline__ float bf2f(unsigned short u){ unsigned x=((unsigned)u)<<16; return __builtin_bit_cast(float,x); }
__device__ __forceinline__ unsigned short f2bf(float f){ unsigned x=__builtin_bit_cast(unsigned,f); return (unsigned short)((x+0x7fffu+((x>>16)&1u))>>16); }
__device__ __forceinline__ float sigmoidf(float x){ return __builtin_amdgcn_rcpf(1.0f + __expf(-x)); }

// ---- K1: fp32 -> bf16 (weights only), 8 elems/thread ----
__global__ void cvt_bf16(const float* __restrict__ src, unsigned short* __restrict__ dst, int n8){
  int i = blockIdx.x*blockDim.x + threadIdx.x;
  if (i>=n8) return;
  const float4* s = reinterpret_cast<const float4*>(src);
  float4 a = s[i*2], b = s[i*2+1];
  uint4 o;
  o.x = (unsigned)f2bf(a.x) | ((unsigned)f2bf(a.y)<<16);
  o.y = (unsigned)f2bf(a.z) | ((unsigned)f2bf(a.w)<<16);
  o.z = (unsigned)f2bf(b.x) | ((unsigned)f2bf(b.y)<<16);
  o.w = (unsigned)f2bf(b.z) | ((unsigned)f2bf(b.w)<<16);
  reinterpret_cast<uint4*>(dst)[i] = o;
}

// ---- K2: dense GEMM  px[m][w][col] = prev[m,:] @ W_w^T  (bf16 in/out, f32 acc)
// block = 128 rows x 128 cols, blockIdx.y = w*2 + col-half. 4 waves, wave-tile 64x64.
__global__ __launch_bounds__(256, 4)
void gemm_dense(const float* __restrict__ prev,
                const unsigned short* __restrict__ wb,   // [4][256][256] bf16 (A,U,V,B)
                unsigned short* __restrict__ px,         // [N][4][256] bf16
                int n)
{
  __shared__ unsigned short As[128*64];   // 16KB, XOR-swizzled
  __shared__ unsigned short Bs[128*64];   // 16KB, XOR-swizzled
  const int tid = threadIdx.x;
  const int m0  = blockIdx.x * 128;
  const int w   = blockIdx.y >> 1;
  const int h   = blockIdx.y & 1;
  const unsigned short* W = wb + w*65536 + (size_t)h*128*HH;
  const int lane = tid & 63, wid = tid >> 6;
  const int wr = wid >> 1, wc = wid & 1;
  const int lm = lane & 15, kc = lane >> 4;

  f32x4 acc[4][4];
  #pragma unroll
  for (int i=0;i<4;++i)
    #pragma unroll
    for (int j=0;j<4;++j) acc[i][j]=(f32x4){0.f,0.f,0.f,0.f};

  for (int ks=0; ks<4; ++ks){
    __syncthreads();   // previous step's frag reads done
    // stage A: rows [m0,m0+128), k [ks*64,+64) from f32, cvt in-register
    #pragma unroll
    for (int i=0;i<4;++i){
      const int c = i*256 + tid;          // 1024 chunks of 8 elems
      const int row = c>>3, kch = c&7;
      const int gm = m0 + row;
      uint4 o = {0u,0u,0u,0u};
      if (gm < n){
        const float4* sp = reinterpret_cast<const float4*>(prev + (size_t)gm*HH + ks*64 + kch*8);
        float4 f0 = sp[0], f1 = sp[1];
        o.x=(unsigned)f2bf(f0.x)|((unsigned)f2bf(f0.y)<<16);
        o.y=(unsigned)f2bf(f0.z)|((unsigned)f2bf(f0.w)<<16);
        o.z=(unsigned)f2bf(f1.x)|((unsigned)f2bf(f1.y)<<16);
        o.w=(unsigned)f2bf(f1.z)|((unsigned)f2bf(f1.w)<<16);
      }
      const int byte = row*128 + ((kch*16) ^ ((row&7)<<4));
      *reinterpret_cast<uint4*>(reinterpret_cast<char*>(As)+byte) = o;
    }
    // stage B: W rows (output cols) [h*128,+128), k [ks*64,+64), bf16
    #pragma unroll
    for (int i=0;i<4;++i){
      const int c = i*256 + tid;
      const int row = c>>3, kch = c&7;
      uint4 v = *reinterpret_cast<const uint4*>(W + (size_t)row*HH + ks*64 + kch*8);
      const int byte = row*128 + ((kch*16) ^ ((row&7)<<4));
      *reinterpret_cast<uint4*>(reinterpret_cast<char*>(Bs)+byte) = v;
    }
    __syncthreads();
    #pragma unroll
    for (int kk=0; kk<2; ++kk){
      s16x8 af[4];
      #pragma unroll
      for (int f=0; f<4; ++f){
        const int row = wr*64 + f*16 + lm;
        af[f] = *reinterpret_cast<const s16x8*>(reinterpret_cast<const char*>(As)
                  + row*128 + ((kk*64 + kc*16) ^ ((row&7)<<4)));
      }
      #pragma unroll
      for (int j=0; j<4; ++j){
        const int row = wc*64 + j*16 + lm;
        s16x8 bf = *reinterpret_cast<const s16x8*>(reinterpret_cast<const char*>(Bs)
                  + row*128 + ((kk*64 + kc*16) ^ ((row&7)<<4)));
        #pragma unroll
        for (int i=0; i<4; ++i)
          acc[i][j] = __builtin_amdgcn_mfma_f32_16x16x32_bf16(af[i], bf, acc[i][j], 0, 0, 0);
      }
    }
  }

  // D write: col=lane&15, row=(lane>>4)*4+reg
  #pragma unroll
  for (int i=0;i<4;++i){
    #pragma unroll
    for (int r=0;r<4;++r){
      const int gm = m0 + wr*64 + i*16 + kc*4 + r;
      if (gm < n){
        const size_t base = (size_t)gm*1024 + w*256 + h*128 + wc*64;
        #pragma unroll
        for (int j=0;j<4;++j)
          px[base + j*16 + lm] = f2bf(acc[i][j][r]);
      }
    }
  }
}

// ---- K3: gather epilogue.  32 lanes per node-row, 8 cols/lane.
__global__ __launch_bounds__(256)
void epilogue(const unsigned short* __restrict__ px,   // [N][4][256]: A,U,V,B
              const int* __restrict__ parent,
              const int* __restrict__ child,
              const int* __restrict__ mask,
              float* __restrict__ out,
              int n)
{
  const int e = blockIdx.x*8 + (threadIdx.x>>5);
  if (e >= n) return;
  const int c8 = (threadIdx.x & 31) * 8;
  const int p  = parent[e];

  const unsigned short* rp = px + (size_t)p*1024 + c8;
  uint4 av = *reinterpret_cast<const uint4*>(rp);         // PA
  uint4 uv = *reinterpret_cast<const uint4*>(rp + 256);   // PU
  const unsigned short* ap = reinterpret_cast<const unsigned short*>(&av);
  const unsigned short* up = reinterpret_cast<const unsigned short*>(&uv);

  float A[8], o[8], eta[8];
  #pragma unroll
  for (int j=0;j<8;++j){ A[j]=bf2f(ap[j]); o[j]=bf2f(up[j]); eta[j]=0.f; }

  int nm = 0;
  #pragma unroll
  for (int k=0;k<KK;++k){
    if (mask[(size_t)e*KK + k]){
      const unsigned short* rc = px + (size_t)child[(size_t)e*KK + k]*1024 + c8;
      uint4 pv = *reinterpret_cast<const uint4*>(rc + 512);   // PV
      uint4 pb = *reinterpret_cast<const uint4*>(rc + 768);   // PB
      const unsigned short* vp = reinterpret_cast<const unsigned short*>(&pv);
      const unsigned short* bp = reinterpret_cast<const unsigned short*>(&pb);
      #pragma unroll
      for (int j=0;j<8;++j){
        o[j]   += bf2f(vp[j]);
        eta[j] += sigmoidf(A[j] + bf2f(bp[j]));
      }
    } else ++nm;
  }

  const float fnm = (float)nm;
  #pragma unroll
  for (int j=0;j<8;++j){
    float s = o[j] + eta[j] + fnm * sigmoidf(A[j]);
    out[(size_t)p*HH + c8 + j] = s > 0.f ? s : 0.f;
  }
}

extern "C" void kernel_launch(void* const* d_in, const int* in_sizes, int n_in,
                              void* d_out, int out_size, void* d_ws, size_t ws_size,
                              hipStream_t stream)
{
  const float* prev = (const float*)d_in[0];
  const float* W_U  = (const float*)d_in[1];
  const float* W_V  = (const float*)d_in[2];
  const float* W_A  = (const float*)d_in[3];
  const float* W_B  = (const float*)d_in[4];
  const int* parent = (const int*)d_in[5];
  const int* child  = (const int*)d_in[6];
  const int* mask   = (const int*)d_in[7];
  float* out = (float*)d_out;

  const int n_nodes = in_sizes[5];

  unsigned short* wb = (unsigned short*)d_ws;      // [4][256][256] bf16 (A,U,V,B) = 512KB
  unsigned short* px = wb + 4*65536;               // [N][4][256] bf16 = 205MB

  // K1: weight conversions (order: A, U, V, B)
  {
    const int w8 = 65536/8;
    cvt_bf16<<<(w8+255)/256, 256, 0, stream>>>(W_A, wb,           w8);
    cvt_bf16<<<(w8+255)/256, 256, 0, stream>>>(W_U, wb + 65536,   w8);
    cvt_bf16<<<(w8+255)/256, 256, 0, stream>>>(W_V, wb + 2*65536, w8);
    cvt_bf16<<<(w8+255)/256, 256, 0, stream>>>(W_B, wb + 3*65536, w8);
  }

  // K2: 4 dense GEMMs in one dispatch
  dim3 g2((n_nodes + 127)/128, 8);
  gemm_dense<<<g2, 256, 0, stream>>>(prev, wb, px, n_nodes);

  hipMemsetAsync(d_out, 0, (size_t)out_size * sizeof(float), stream);

  // K3: gather + eta + relu + scatter
  epilogue<<<(n_nodes + 7)/8, 256, 0, stream>>>(px, parent, child, mask, out, n_nodes);
}

// Round 6
// 216.032 us; speedup vs baseline: 24.8545x; 1.6398x over previous
//
#include <hip/hip_runtime.h>

#define HH 256
#define KK 8

typedef __attribute__((ext_vector_type(8))) short s16x8;
typedef __attribute__((ext_vector_type(4))) float f32x4;

__device__ __forceinline__ float bf2f(unsigned short u){ unsigned x=((unsigned)u)<<16; return __builtin_bit_cast(float,x); }
__device__ __forceinline__ unsigned short f2bf(float f){ unsigned x=__builtin_bit_cast(unsigned,f); return (unsigned short)((x+0x7fffu+((x>>16)&1u))>>16); }
__device__ __forceinline__ float sigmoidf(float x){ return __builtin_amdgcn_rcpf(1.0f + __expf(-x)); }

// ---- K1: fp32 -> bf16 (weights only) ----
__global__ void cvt_bf16(const float* __restrict__ src, unsigned short* __restrict__ dst, int n8){
  int i = blockIdx.x*blockDim.x + threadIdx.x;
  if (i>=n8) return;
  const float4* s = reinterpret_cast<const float4*>(src);
  float4 a = s[i*2], b = s[i*2+1];
  uint4 o;
  o.x = (unsigned)f2bf(a.x) | ((unsigned)f2bf(a.y)<<16);
  o.y = (unsigned)f2bf(a.z) | ((unsigned)f2bf(a.w)<<16);
  o.z = (unsigned)f2bf(b.x) | ((unsigned)f2bf(b.y)<<16);
  o.w = (unsigned)f2bf(b.z) | ((unsigned)f2bf(b.w)<<16);
  reinterpret_cast<uint4*>(dst)[i] = o;
}

// ---- K2: px[m][w][col] = prev[m,:] @ W_w^T for all 4 w.  A-tile read ONCE per block.
// 512 thr / 8 waves; block = 128 rows x 1024 out-cols (8 groups of 128); wave-tile 32x64.
__global__ __launch_bounds__(512, 2)
void gemm_all(const float* __restrict__ prev,
              const unsigned short* __restrict__ wb,   // [4][256][256] bf16 (A,U,V,B)
              unsigned short* __restrict__ px,         // [N][4][256] bf16
              int n)
{
  __shared__ unsigned short As[128*HH];    // 64KB, swizzled
  __shared__ unsigned short Bs[128*64];    // 16KB, swizzled
  const int tid = threadIdx.x;
  const int m0  = blockIdx.x * 128;

  // stage A-tile: 128 rows x 256 k, f32 -> bf16, swizzled (byte ^= (row&7)<<4)
  #pragma unroll
  for (int it=0; it<8; ++it){
    const int c = it*512 + tid;
    const int row = c>>5, kch = c&31;
    const int gm = m0 + row;
    uint4 o = {0u,0u,0u,0u};
    if (gm < n){
      const float4* sp = reinterpret_cast<const float4*>(prev + (size_t)gm*HH + kch*8);
      float4 f0 = sp[0], f1 = sp[1];
      o.x=(unsigned)f2bf(f0.x)|((unsigned)f2bf(f0.y)<<16);
      o.y=(unsigned)f2bf(f0.z)|((unsigned)f2bf(f0.w)<<16);
      o.z=(unsigned)f2bf(f1.x)|((unsigned)f2bf(f1.y)<<16);
      o.w=(unsigned)f2bf(f1.z)|((unsigned)f2bf(f1.w)<<16);
    }
    const int byte = row*512 + ((kch*16) ^ ((row&7)<<4));
    *reinterpret_cast<uint4*>(reinterpret_cast<char*>(As)+byte) = o;
  }

  const int lane=tid&63, wid=tid>>6;
  const int wr=wid>>1, wc=wid&1;           // 4 row-groups(32) x 2 col-halves(64)
  const int lm=lane&15, kc=lane>>4;

  // Bs staging coords: thread covers rows nn0 and nn0+64, k-chunk kch0
  const int nn0 = tid>>3, kch0 = tid&7;
  const int bb0 = nn0*128 + ((kch0*16) ^ ((nn0&7)<<4));   // (nn0+64)&7 == nn0&7 -> +8192

  // prefetch step 0 (g=0, ks=0)
  uint4 w0 = *reinterpret_cast<const uint4*>(wb + (size_t)nn0*HH + kch0*8);
  uint4 w1 = *reinterpret_cast<const uint4*>(wb + (size_t)(nn0+64)*HH + kch0*8);

  f32x4 acc[2][4];

  for (int step=0; step<32; ++step){
    const int g = step>>2, ks = step&3;
    __syncthreads();                         // prior readers of Bs done
    *reinterpret_cast<uint4*>(reinterpret_cast<char*>(Bs)+bb0)        = w0;
    *reinterpret_cast<uint4*>(reinterpret_cast<char*>(Bs)+bb0+8192)   = w1;
    __syncthreads();                         // Bs visible
    if (step < 31){                          // prefetch next panel during compute
      const int s2 = step+1, g2 = s2>>2, ks2 = s2&3;
      const unsigned short* W = wb + (g2>>1)*65536 + (size_t)(g2&1)*128*HH + ks2*64;
      w0 = *reinterpret_cast<const uint4*>(W + (size_t)nn0*HH + kch0*8);
      w1 = *reinterpret_cast<const uint4*>(W + (size_t)(nn0+64)*HH + kch0*8);
    }
    if (ks==0){
      #pragma unroll
      for (int i=0;i<2;++i)
        #pragma unroll
        for (int j=0;j<4;++j) acc[i][j]=(f32x4){0.f,0.f,0.f,0.f};
    }
    #pragma unroll
    for (int kk=0; kk<2; ++kk){
      s16x8 af[2];
      #pragma unroll
      for (int i=0;i<2;++i){
        const int row = wr*32 + i*16 + lm;
        af[i] = *reinterpret_cast<const s16x8*>(reinterpret_cast<const char*>(As)
                  + row*512 + ((ks*128 + kk*64 + kc*16) ^ ((row&7)<<4)));
      }
      #pragma unroll
      for (int j=0; j<4; ++j){
        const int brow = wc*64 + j*16 + lm;
        s16x8 bf = *reinterpret_cast<const s16x8*>(reinterpret_cast<const char*>(Bs)
                  + brow*128 + ((kk*64 + kc*16) ^ ((brow&7)<<4)));
        #pragma unroll
        for (int i=0;i<2;++i)
          acc[i][j] = __builtin_amdgcn_mfma_f32_16x16x32_bf16(af[i], bf, acc[i][j], 0, 0, 0);
      }
    }
    if (ks==3){                              // flush this group's D
      const int w_ = g>>1, h_ = g&1;
      #pragma unroll
      for (int i=0;i<2;++i){
        #pragma unroll
        for (int r=0;r<4;++r){
          const int gm = m0 + wr*32 + i*16 + kc*4 + r;   // D: row=(lane>>4)*4+reg
          if (gm < n){
            const size_t base = (size_t)gm*1024 + w_*256 + h_*128 + wc*64;
            #pragma unroll
            for (int j=0;j<4;++j)
              px[base + j*16 + lm] = f2bf(acc[i][j][r]);
          }
        }
      }
    }
  }
}

// ---- K3: gather epilogue. 32 lanes per node-row, 8 cols/lane. Writes EVERY row. ----
__global__ __launch_bounds__(256)
void epilogue(const unsigned short* __restrict__ px,   // [N][4][256]: A,U,V,B
              const int* __restrict__ parent,
              const int* __restrict__ child,
              const int* __restrict__ mask,
              float* __restrict__ out,
              int n)
{
  const int e = blockIdx.x*8 + (threadIdx.x>>5);
  if (e >= n) return;
  const int c8 = (threadIdx.x & 31) * 8;
  const int p  = parent[e];

  const unsigned short* rp = px + (size_t)p*1024 + c8;
  uint4 av = *reinterpret_cast<const uint4*>(rp);         // PA
  uint4 uv = *reinterpret_cast<const uint4*>(rp + 256);   // PU
  const unsigned short* ap = reinterpret_cast<const unsigned short*>(&av);
  const unsigned short* up = reinterpret_cast<const unsigned short*>(&uv);

  float A[8], o[8], eta[8];
  #pragma unroll
  for (int j=0;j<8;++j){ A[j]=bf2f(ap[j]); o[j]=bf2f(up[j]); eta[j]=0.f; }

  int nm = 0;
  #pragma unroll
  for (int k=0;k<KK;++k){
    if (mask[(size_t)e*KK + k]){
      const unsigned short* rc = px + (size_t)child[(size_t)e*KK + k]*1024 + c8;
      uint4 pv = *reinterpret_cast<const uint4*>(rc + 512);   // PV
      uint4 pb = *reinterpret_cast<const uint4*>(rc + 768);   // PB
      const unsigned short* vp = reinterpret_cast<const unsigned short*>(&pv);
      const unsigned short* bp = reinterpret_cast<const unsigned short*>(&pb);
      #pragma unroll
      for (int j=0;j<8;++j){
        o[j]   += bf2f(vp[j]);
        eta[j] += sigmoidf(A[j] + bf2f(bp[j]));
      }
    } else ++nm;
  }

  const float fnm = (float)nm;
  #pragma unroll
  for (int j=0;j<8;++j){
    float s = o[j] + eta[j] + fnm * sigmoidf(A[j]);
    out[(size_t)p*HH + c8 + j] = s > 0.f ? s : 0.f;
  }
}

extern "C" void kernel_launch(void* const* d_in, const int* in_sizes, int n_in,
                              void* d_out, int out_size, void* d_ws, size_t ws_size,
                              hipStream_t stream)
{
  const float* prev = (const float*)d_in[0];
  const float* W_U  = (const float*)d_in[1];
  const float* W_V  = (const float*)d_in[2];
  const float* W_A  = (const float*)d_in[3];
  const float* W_B  = (const float*)d_in[4];
  const int* parent = (const int*)d_in[5];
  const int* child  = (const int*)d_in[6];
  const int* mask   = (const int*)d_in[7];
  float* out = (float*)d_out;

  const int n_nodes = in_sizes[5];

  unsigned short* wb = (unsigned short*)d_ws;      // [4][256][256] bf16 (A,U,V,B) = 512KB
  unsigned short* px = wb + 4*65536;               // [N][4][256] bf16 = 205MB

  // K1: weight conversions (order: A, U, V, B)
  {
    const int w8 = 65536/8;
    cvt_bf16<<<(w8+255)/256, 256, 0, stream>>>(W_A, wb,           w8);
    cvt_bf16<<<(w8+255)/256, 256, 0, stream>>>(W_U, wb + 65536,   w8);
    cvt_bf16<<<(w8+255)/256, 256, 0, stream>>>(W_V, wb + 2*65536, w8);
    cvt_bf16<<<(w8+255)/256, 256, 0, stream>>>(W_B, wb + 3*65536, w8);
  }

  // K2: all 4 projections, prev read once
  gemm_all<<<(n_nodes + 127)/128, 512, 0, stream>>>(prev, wb, px, n_nodes);

  // K3: gather + eta + relu + scatter (writes every row; parent is a permutation)
  epilogue<<<(n_nodes + 7)/8, 256, 0, stream>>>(px, parent, child, mask, out, n_nodes);
}